// Round 3
// baseline (208.205 us; speedup 1.0000x reference)
//
#include <hip/hip_runtime.h>

typedef unsigned short u16;
typedef __attribute__((ext_vector_type(8))) short bf16x8;
typedef __attribute__((ext_vector_type(4))) float f32x4;

#define B_   8
#define S_   2048
#define IN_  256
#define D_   1024
#define OUT_ 256
#define KC_  32          // flash k-chunks
#define RC_  64          // rows per chunk

// ---- workspace offsets (bytes), total ~38.3 MB ----
#define OFF_WITB  0UL          // WiT tiled-swizzled bf16: 8 tiles x 4 ksteps x 8192 u16 = 512K
#define OFF_H     524288UL     // h bf16 [16384][1024] = 32M
#define OFF_AMAT  34078720UL   // Amat bf16 [1024][1024] = 2M   (Wq @ Wk^T)
#define OFF_AWO   36175872UL   // Awo f32 [1024][256] = 1M      (Wv @ WoT^T)
#define OFF_WOTB  37224448UL   // WoT tiled-swizzled bf16: 2 x 16 x 8192 u16 = 512K
#define OFF_C     37748736UL   // cvec 1024 f32
#define OFF_CVOP  37752832UL   // 16x256 f32
#define OFF_CVO   37769216UL   // 256 f32
#define OFF_U     37770240UL   // 8x1024 f32
#define OFF_PART  37803008UL   // 256x1024 f32 = 1M
#define OFF_MSUM  38851584UL   // 256x2 f32

static __device__ __forceinline__ float bf2f(u16 u) {
    union { unsigned i; float f; } x; x.i = ((unsigned)u) << 16; return x.f;
}
static __device__ __forceinline__ u16 f2bf(float f) {
    union { float f; unsigned i; } x; x.f = f;
    unsigned r = x.i + 0x7FFFu + ((x.i >> 16) & 1u);
    return (u16)(r >> 16);
}
static __device__ __forceinline__ float2 bf2x2(int p) {
    union { unsigned i; float f; } a, b;
    a.i = ((unsigned)p) << 16;
    b.i = ((unsigned)p) & 0xFFFF0000u;
    float2 r; r.x = a.f; r.y = b.f; return r;
}

// Tiled-swizzled bf16 operand layout: element (rr in [0,128), cc in [0,64)) of tile
// (tr, ks) lives at u16 index (tr*KT + ks)*8192 + rr*64 + (((cc>>3) ^ (rr&7))<<3) + (cc&7).

// ================= K1: WiT/WoT transpose+convert (tiled swizzled), cvec, cvop =================
__global__ __launch_bounds__(256) void k1(const float* __restrict__ Wi, u16* __restrict__ WiTb,
                                          const float* __restrict__ Wo, u16* __restrict__ WoTb,
                                          const float* __restrict__ Wk, const float* __restrict__ bq,
                                          float* __restrict__ cvec,
                                          const float* __restrict__ bv, float* __restrict__ cvop) {
    __shared__ float t64[64][65];
    const int blk = blockIdx.x, tid = threadIdx.x;
    if (blk < 64) {
        // WiT[n][k] = Wi[k][n]; Wi is [256][1024].  Output tiles: KT=4.
        const int n0 = (blk & 15) * 64, k0 = (blk >> 4) * 64;
        const int cc = tid & 63, rr = tid >> 6;
#pragma unroll
        for (int p = 0; p < 16; ++p) { int r = p * 4 + rr; t64[r][cc] = Wi[(k0 + r) * 1024 + n0 + cc]; }
        __syncthreads();
        const int ks = k0 >> 6;
#pragma unroll
        for (int g = 0; g < 2; ++g) {
            int it = g * 256 + tid;
            int nn = it >> 3, grp = it & 7;
            int n = n0 + nn, tr = n >> 7, rrow = n & 127;
            int4 pk;
            pk.x = (int)f2bf(t64[grp * 8 + 0][nn]) | ((int)f2bf(t64[grp * 8 + 1][nn]) << 16);
            pk.y = (int)f2bf(t64[grp * 8 + 2][nn]) | ((int)f2bf(t64[grp * 8 + 3][nn]) << 16);
            pk.z = (int)f2bf(t64[grp * 8 + 4][nn]) | ((int)f2bf(t64[grp * 8 + 5][nn]) << 16);
            pk.w = (int)f2bf(t64[grp * 8 + 6][nn]) | ((int)f2bf(t64[grp * 8 + 7][nn]) << 16);
            *reinterpret_cast<int4*>(&WiTb[(size_t)(tr * 4 + ks) * 8192 + rrow * 64 + ((grp ^ (rrow & 7)) << 3)]) = pk;
        }
    } else if (blk < 128) {
        // WoT[o][e] = Wo[e][o]; Wo is [1024][256].  Output tiles: KT=16.
        const int t = blk - 64;
        const int o0 = (t & 3) * 64, e0 = (t >> 2) * 64;
        const int cc = tid & 63, rr = tid >> 6;
#pragma unroll
        for (int p = 0; p < 16; ++p) { int r = p * 4 + rr; t64[r][cc] = Wo[(e0 + r) * 256 + o0 + cc]; }
        __syncthreads();
        const int ks = e0 >> 6;
#pragma unroll
        for (int g = 0; g < 2; ++g) {
            int it = g * 256 + tid;
            int nn = it >> 3, grp = it & 7;
            int o = o0 + nn, tr = o >> 7, rrow = o & 127;
            int4 pk;
            pk.x = (int)f2bf(t64[grp * 8 + 0][nn]) | ((int)f2bf(t64[grp * 8 + 1][nn]) << 16);
            pk.y = (int)f2bf(t64[grp * 8 + 2][nn]) | ((int)f2bf(t64[grp * 8 + 3][nn]) << 16);
            pk.z = (int)f2bf(t64[grp * 8 + 4][nn]) | ((int)f2bf(t64[grp * 8 + 5][nn]) << 16);
            pk.w = (int)f2bf(t64[grp * 8 + 6][nn]) | ((int)f2bf(t64[grp * 8 + 7][nn]) << 16);
            *reinterpret_cast<int4*>(&WoTb[(size_t)(tr * 16 + ks) * 8192 + rrow * 64 + ((grp ^ (rrow & 7)) << 3)]) = pk;
        }
    } else if (blk < 192) {
        // cvec[d] = sum_e Wk[d][e] * bq[e]
        const int b2 = blk - 128;
        const int w = tid >> 6, l = tid & 63;
        const int dbase = b2 * 16 + w * 4;
        float4 qv[4];
#pragma unroll
        for (int p = 0; p < 4; ++p) qv[p] = *reinterpret_cast<const float4*>(&bq[p * 256 + l * 4]);
#pragma unroll
        for (int i = 0; i < 4; ++i) {
            const int d = dbase + i;
            const float* wr = &Wk[(size_t)d * 1024];
            float acc = 0.f;
#pragma unroll
            for (int p = 0; p < 4; ++p) {
                float4 wv = *reinterpret_cast<const float4*>(&wr[p * 256 + l * 4]);
                acc += wv.x * qv[p].x + wv.y * qv[p].y + wv.z * qv[p].z + wv.w * qv[p].w;
            }
#pragma unroll
            for (int s = 32; s > 0; s >>= 1) acc += __shfl_xor(acc, s);
            if (l == 0) cvec[d] = acc;
        }
    } else {
        // cvop[chunk][o] = sum_{e in chunk} bv[e]*Wo[e][o]
        const int b2 = blk - 192;
        const int e0 = b2 * 64;
        float acc = 0.f;
        for (int e = 0; e < 64; ++e) acc += bv[e0 + e] * Wo[(size_t)(e0 + e) * 256 + tid];
        cvop[b2 * 256 + tid] = acc;
    }
}

// ---------------- staging helpers ----------------
static __device__ __forceinline__ void stage_bf(const u16* gtile, u16* lbuf, int w, int l) {
    // pre-swizzled bf16 tile (16 KB) -> LDS, linear DMA copy
    const u16* g = gtile + w * 512 + l * 8;
    u16* lp = lbuf + w * 512;
#pragma unroll
    for (int i = 0; i < 4; ++i)
        __builtin_amdgcn_global_load_lds((const __attribute__((address_space(1))) void*)(g + i * 2048),
                                         (__attribute__((address_space(3))) void*)(lp + i * 2048), 16, 0, 0);
}
static __device__ __forceinline__ void stage_f32(const float* src, int lds_, int ks, u16* lbuf, int tid) {
    // f32 row-major [128+ rows][lds_ cols] -> bf16 swizzled LDS tile (128x64)
#pragma unroll
    for (int i = 0; i < 4; ++i) {
        int it = i * 256 + tid;
        int row = it >> 3, grp = it & 7;
        const float4* p = reinterpret_cast<const float4*>(&src[(size_t)row * lds_ + ks * 64 + grp * 8]);
        float4 v0 = p[0], v1 = p[1];
        int4 pk;
        pk.x = (int)f2bf(v0.x) | ((int)f2bf(v0.y) << 16);
        pk.y = (int)f2bf(v0.z) | ((int)f2bf(v0.w) << 16);
        pk.z = (int)f2bf(v1.x) | ((int)f2bf(v1.y) << 16);
        pk.w = (int)f2bf(v1.z) | ((int)f2bf(v1.w) << 16);
        *reinterpret_cast<int4*>(&lbuf[row * 64 + ((grp ^ (row & 7)) << 3)]) = pk;
    }
}

// ---------------- generic 128x128 MFMA tile, BK=64, single-buffer ----------------
// AMODE/BMODE: 0 = bf16 pre-swizzled tiles (global_load_lds), 1 = f32 reg-stage
// OMODE: 0 = bf16 + bias, 1 = bf16 no bias, 2 = f32 no bias
template<int KT, int AMODE, int BMODE, int OMODE>
static __device__ __forceinline__ void mm128(
    const float* Af, int lda, const u16* Ab,
    const float* Bf, int ldb, const u16* Bb,
    u16* lA, u16* lB,
    const float* __restrict__ bias,
    u16* __restrict__ outb, float* __restrict__ outf, int ldo)
{
    const int tid = threadIdx.x, l = tid & 63, w = tid >> 6;
    const int wm = w >> 1, wn = w & 1;
    const int q = l >> 4, r = l & 15;
    f32x4 acc[4][4];
#pragma unroll
    for (int mt = 0; mt < 4; ++mt)
#pragma unroll
        for (int nt = 0; nt < 4; ++nt) acc[mt][nt] = (f32x4){0.f, 0.f, 0.f, 0.f};

    for (int ks = 0; ks < KT; ++ks) {
        if (ks) __syncthreads();
        if constexpr (AMODE == 1) stage_f32(Af, lda, ks, lA, tid);
        else                      stage_bf(Ab + (size_t)ks * 8192, lA, w, l);
        if constexpr (BMODE == 1) stage_f32(Bf, ldb, ks, lB, tid);
        else                      stage_bf(Bb + (size_t)ks * 8192, lB, w, l);
        __syncthreads();   // drains vmcnt (global_load_lds) + lgkm (ds_write)
#pragma unroll
        for (int s = 0; s < 2; ++s) {
            bf16x8 af[4], bfr[4];
#pragma unroll
            for (int mt = 0; mt < 4; ++mt) {
                int row = wm * 64 + mt * 16 + r;
                af[mt] = *reinterpret_cast<const bf16x8*>(&lA[row * 64 + (((s * 4 + q) ^ (row & 7)) << 3)]);
            }
#pragma unroll
            for (int nt = 0; nt < 4; ++nt) {
                int row = wn * 64 + nt * 16 + r;
                bfr[nt] = *reinterpret_cast<const bf16x8*>(&lB[row * 64 + (((s * 4 + q) ^ (row & 7)) << 3)]);
            }
#pragma unroll
            for (int mt = 0; mt < 4; ++mt)
#pragma unroll
                for (int nt = 0; nt < 4; ++nt)
                    acc[mt][nt] = __builtin_amdgcn_mfma_f32_16x16x32_bf16(af[mt], bfr[nt], acc[mt][nt], 0, 0, 0);
        }
    }
    // epilogue.  C/D map: col=lane&15, row=(lane>>4)*4+j
#pragma unroll
    for (int nt = 0; nt < 4; ++nt) {
        int col = wn * 64 + nt * 16 + r;
        float bb = 0.f;
        if constexpr (OMODE == 0) bb = bias[col];
#pragma unroll
        for (int mt = 0; mt < 4; ++mt) {
#pragma unroll
            for (int j = 0; j < 4; ++j) {
                int row = wm * 64 + mt * 16 + q * 4 + j;
                float v = acc[mt][nt][j] + bb;
                if constexpr (OMODE == 2) outf[(size_t)row * ldo + col] = v;
                else                      outb[(size_t)row * ldo + col] = f2bf(v);
            }
        }
    }
}

// ================= K2: h-GEMM || Amat=Wq@Wk^T || Awo=Wv@WoT^T =================
__global__ __launch_bounds__(256) void k2(const float* __restrict__ x, const u16* __restrict__ WiTb,
                                          const float* __restrict__ bi, u16* __restrict__ h,
                                          const float* __restrict__ Wq, const float* __restrict__ Wk,
                                          u16* __restrict__ Amat,
                                          const float* __restrict__ Wv, const u16* __restrict__ WoTb,
                                          float* __restrict__ Awo) {
    __shared__ u16 lA[8192];
    __shared__ u16 lB[8192];
    const int blk = blockIdx.x;
    if (blk < 1024) {
        // XCD-aware: xcd = blk&7 owns m-strip [xcd*16, xcd*16+16); n fastest within strip.
        const int xcd = blk & 7, j = blk >> 3;
        const int mt = xcd * 16 + (j >> 3), nt = j & 7;
        mm128<4, 1, 0, 0>(x + (size_t)mt * 128 * IN_, IN_, nullptr,
                          nullptr, 0, WiTb + (size_t)nt * 4 * 8192,
                          lA, lB, bi + nt * 128,
                          h + (size_t)mt * 128 * D_ + nt * 128, nullptr, D_);
    } else if (blk < 1088) {
        const int t = blk - 1024;
        const int mt = t >> 3, nt = t & 7;
        mm128<16, 1, 1, 1>(Wq + (size_t)mt * 128 * D_, D_, nullptr,
                           Wk + (size_t)nt * 128 * D_, D_, nullptr,
                           lA, lB, nullptr,
                           Amat + (size_t)mt * 128 * D_ + nt * 128, nullptr, D_);
    } else {
        const int t = blk - 1088;
        const int mt = t >> 1, nt = t & 1;
        mm128<16, 1, 0, 2>(Wv + (size_t)mt * 128 * D_, D_, nullptr,
                           nullptr, 0, WoTb + (size_t)nt * 16 * 8192,
                           lA, lB, nullptr,
                           nullptr, Awo + (size_t)mt * 128 * OUT_ + nt * 128, OUT_);
    }
}

// ================= K3: u[b] = h_last[b] @ Amat + cvec ; cvo finish =================
__global__ __launch_bounds__(256) void k3(const u16* __restrict__ h, const u16* __restrict__ Amat,
                                          const float* __restrict__ cvec, float* __restrict__ u,
                                          const float* __restrict__ cvop, const float* __restrict__ bo,
                                          float* __restrict__ cvo) {
    const int blk = blockIdx.x, tid = threadIdx.x;
    if (blk < 128) {
        const int b = blk >> 4, dc = blk & 15;
        __shared__ float hl[1024];
        __shared__ float red[4][64];
        {
            const size_t hb = ((size_t)(b * S_ + S_ - 1)) * D_;
            int2 hv = *reinterpret_cast<const int2*>(&h[hb + tid * 4]);
            float2 p0 = bf2x2(hv.x), p1 = bf2x2(hv.y);
            hl[tid * 4 + 0] = p0.x; hl[tid * 4 + 1] = p0.y;
            hl[tid * 4 + 2] = p1.x; hl[tid * 4 + 3] = p1.y;
        }
        __syncthreads();
        const int dl = tid & 63, qd = tid >> 6;
        const int d = dc * 64 + dl;
        float ac[8] = {0.f, 0.f, 0.f, 0.f, 0.f, 0.f, 0.f, 0.f};
        for (int dp = qd * 256; dp < qd * 256 + 256; dp += 8) {
            float hh[8];
#pragma unroll
            for (int i = 0; i < 8; ++i) hh[i] = hl[dp + i];
#pragma unroll
            for (int i = 0; i < 8; ++i) ac[i] += hh[i] * bf2f(Amat[(size_t)(dp + i) * D_ + d]);
        }
        float acc = ((ac[0] + ac[1]) + (ac[2] + ac[3])) + ((ac[4] + ac[5]) + (ac[6] + ac[7]));
        red[qd][dl] = acc;
        __syncthreads();
        if (qd == 0) {
            float s = red[0][dl] + red[1][dl] + red[2][dl] + red[3][dl];
            u[b * D_ + d] = s + cvec[d];
        }
    } else {
        float s = bo[tid];
#pragma unroll
        for (int j = 0; j < 16; ++j) s += cvop[j * 256 + tid];
        cvo[tid] = s;
    }
}

// ================= K4: flash partial per (kc, b) over 64 rows =================
__global__ __launch_bounds__(256) void k4(const u16* __restrict__ h, const float* __restrict__ u,
                                          float* __restrict__ part, float* __restrict__ msum) {
    const int kc = blockIdx.x, b = blockIdx.y;
    const int tid = threadIdx.x, w = tid >> 6, l = tid & 63;
    __shared__ float sNp[RC_];
    float uv[16];
    {
        const float* ub = &u[b * D_ + l * 16];
#pragma unroll
        for (int p = 0; p < 4; ++p) {
            float4 v = *reinterpret_cast<const float4*>(&ub[p * 4]);
            uv[p * 4 + 0] = v.x; uv[p * 4 + 1] = v.y; uv[p * 4 + 2] = v.z; uv[p * 4 + 3] = v.w;
        }
    }
    const size_t base = ((size_t)(b * S_) + kc * RC_) * D_;
    for (int rr = 0; rr < 16; ++rr) {
        const int row = w * 16 + rr;
        const u16* hr = &h[base + (size_t)row * D_ + l * 16];
        int4 q0 = *reinterpret_cast<const int4*>(&hr[0]);
        int4 q1 = *reinterpret_cast<const int4*>(&hr[8]);
        float2 a0 = bf2x2(q0.x), a1 = bf2x2(q0.y), a2 = bf2x2(q0.z), a3 = bf2x2(q0.w);
        float2 c0 = bf2x2(q1.x), c1 = bf2x2(q1.y), c2 = bf2x2(q1.z), c3 = bf2x2(q1.w);
        float acc = a0.x * uv[0] + a0.y * uv[1] + a1.x * uv[2] + a1.y * uv[3]
                  + a2.x * uv[4] + a2.y * uv[5] + a3.x * uv[6] + a3.y * uv[7]
                  + c0.x * uv[8] + c0.y * uv[9] + c1.x * uv[10] + c1.y * uv[11]
                  + c2.x * uv[12] + c2.y * uv[13] + c3.x * uv[14] + c3.y * uv[15];
#pragma unroll
        for (int s = 32; s > 0; s >>= 1) acc += __shfl_xor(acc, s);
        if (l == 0) sNp[row] = acc * 0.03125f;   // 1/sqrt(1024)
    }
    __syncthreads();
    float sv = sNp[l];
    float mx = sv;
#pragma unroll
    for (int s = 32; s > 0; s >>= 1) mx = fmaxf(mx, __shfl_xor(mx, s));
    float p = __expf(sv - mx);
    float sum = p;
#pragma unroll
    for (int s = 32; s > 0; s >>= 1) sum += __shfl_xor(sum, s);
    __syncthreads();
    if (w == 0) sNp[l] = p;
    if (tid == 0) { msum[(kc * 8 + b) * 2] = mx; msum[(kc * 8 + b) * 2 + 1] = sum; }
    __syncthreads();
    const int d0 = tid * 4;
    float a0 = 0.f, a1 = 0.f, a2 = 0.f, a3 = 0.f;
    for (int k = 0; k < RC_; ++k) {
        float pk = sNp[k];
        int2 hv = *reinterpret_cast<const int2*>(&h[base + (size_t)k * D_ + d0]);
        float2 x0 = bf2x2(hv.x), x1 = bf2x2(hv.y);
        a0 += pk * x0.x; a1 += pk * x0.y; a2 += pk * x1.x; a3 += pk * x1.y;
    }
    float4 st = {a0, a1, a2, a3};
    *reinterpret_cast<float4*>(&part[((size_t)(kc * 8 + b)) * D_ + d0]) = st;
}

// ================= K5: combine partials -> hbar -> out = hbar@Awo + cvo =================
__global__ __launch_bounds__(256) void k5(const float* __restrict__ part, const float* __restrict__ msum,
                                          const float* __restrict__ Awo, const float* __restrict__ cvo,
                                          float* __restrict__ out) {
    const int b = blockIdx.x, tid = threadIdx.x, w = tid >> 6, l = tid & 63;
    __shared__ float hbar[1024];
    __shared__ float red[4][256];
    float m[KC_], sm[KC_];
    float M = -1e30f;
#pragma unroll
    for (int c = 0; c < KC_; ++c) {
        m[c] = msum[(c * 8 + b) * 2];
        sm[c] = msum[(c * 8 + b) * 2 + 1];
        M = fmaxf(M, m[c]);
    }
    float denom = 0.f;
    float wgt[KC_];
#pragma unroll
    for (int c = 0; c < KC_; ++c) { wgt[c] = __expf(m[c] - M); denom += wgt[c] * sm[c]; }
    const float inv = 1.f / denom;
    float h0 = 0.f, h1 = 0.f, h2 = 0.f, h3 = 0.f;
#pragma unroll
    for (int c = 0; c < KC_; ++c) {
        float4 pv = *reinterpret_cast<const float4*>(&part[((size_t)(c * 8 + b)) * D_ + tid * 4]);
        h0 += wgt[c] * pv.x; h1 += wgt[c] * pv.y; h2 += wgt[c] * pv.z; h3 += wgt[c] * pv.w;
    }
    hbar[tid * 4 + 0] = h0 * inv; hbar[tid * 4 + 1] = h1 * inv;
    hbar[tid * 4 + 2] = h2 * inv; hbar[tid * 4 + 3] = h3 * inv;
    __syncthreads();
    float o0 = 0.f, o1 = 0.f, o2 = 0.f, o3 = 0.f;
    for (int d = w * 256; d < w * 256 + 256; d += 4) {
        float4 hv = *reinterpret_cast<const float4*>(&hbar[d]);
#pragma unroll
        for (int j = 0; j < 4; ++j) {
            float hj = (j == 0) ? hv.x : (j == 1) ? hv.y : (j == 2) ? hv.z : hv.w;
            float4 av = *reinterpret_cast<const float4*>(&Awo[(size_t)(d + j) * OUT_ + l * 4]);
            o0 += hj * av.x; o1 += hj * av.y; o2 += hj * av.z; o3 += hj * av.w;
        }
    }
    red[w][l * 4 + 0] = o0; red[w][l * 4 + 1] = o1;
    red[w][l * 4 + 2] = o2; red[w][l * 4 + 3] = o3;
    __syncthreads();
    float r = red[0][tid] + red[1][tid] + red[2][tid] + red[3][tid] + cvo[tid];
    out[b * OUT_ + tid] = r;
}

extern "C" void kernel_launch(void* const* d_in, const int* in_sizes, int n_in,
                              void* d_out, int out_size, void* d_ws, size_t ws_size,
                              hipStream_t stream) {
    const float* x  = (const float*)d_in[0];
    const float* Wi = (const float*)d_in[1];
    const float* bi = (const float*)d_in[2];
    const float* Wq = (const float*)d_in[3];
    const float* bq = (const float*)d_in[4];
    const float* Wk = (const float*)d_in[5];
    // d_in[6] = bk : unused (softmax shift invariance)
    const float* Wv = (const float*)d_in[7];
    const float* bv = (const float*)d_in[8];
    const float* Wo = (const float*)d_in[9];
    const float* bo = (const float*)d_in[10];
    float* out = (float*)d_out;

    char* ws = (char*)d_ws;
    u16*   WiTb = (u16*)  (ws + OFF_WITB);
    u16*   h    = (u16*)  (ws + OFF_H);
    u16*   Amat = (u16*)  (ws + OFF_AMAT);
    float* Awo  = (float*)(ws + OFF_AWO);
    u16*   WoTb = (u16*)  (ws + OFF_WOTB);
    float* cvec = (float*)(ws + OFF_C);
    float* cvop = (float*)(ws + OFF_CVOP);
    float* cvo  = (float*)(ws + OFF_CVO);
    float* uvec = (float*)(ws + OFF_U);
    float* part = (float*)(ws + OFF_PART);
    float* msum = (float*)(ws + OFF_MSUM);

    k1<<<208,        256, 0, stream>>>(Wi, WiTb, Wo, WoTb, Wk, bq, cvec, bv, cvop);
    k2<<<1104,       256, 0, stream>>>(x, WiTb, bi, h, Wq, Wk, Amat, Wv, WoTb, Awo);
    k3<<<129,        256, 0, stream>>>(h, Amat, cvec, uvec, cvop, bo, cvo);
    k4<<<dim3(32,8), 256, 0, stream>>>(h, uvec, part, msum);
    k5<<<8,          256, 0, stream>>>(part, msum, Awo, cvo, out);
}

// Round 5
// 157.121 us; speedup vs baseline: 1.3251x; 1.3251x over previous
//
#include <hip/hip_runtime.h>

typedef unsigned short u16;
typedef __attribute__((ext_vector_type(8))) short bf16x8;
typedef __attribute__((ext_vector_type(4))) float f32x4;

#define B_   8
#define S_   2048
#define IN_  256
#define D_   1024
#define OUT_ 256
#define KC_  32          // flash k-chunks
#define RC_  64          // rows per chunk

// ---- workspace offsets (bytes), total ~53.5 MB ----
#define OFF_WITB  0UL          // WiT tiles: 8 tr x 4 ks x 8192 u16 = 512K
#define OFF_WOTB  524288UL     // WoT tiles: 2 tr x 16 ks x 8192 u16 = 512K
#define OFF_XB    1048576UL    // x tiles: 128 mt x 4 ks x 8192 u16 = 8M
#define OFF_WQB   9437184UL    // Wq tiles: 8 x 16 x 8192 u16 = 2M
#define OFF_WKB   11534336UL   // Wk tiles: 2M
#define OFF_WVB   13631488UL   // Wv tiles: 2M
#define OFF_H     15728640UL   // h bf16 [16384][1024] = 32M
#define OFF_AMAT  49283072UL   // Amat bf16 [1024][1024] = 2M  (Wq @ Wk^T)
#define OFF_AWO   51380224UL   // Awo f32 [1024][256] = 1M     (Wv @ Wo)
#define OFF_C     52428800UL   // cvec 1024 f32
#define OFF_CVOP  52432896UL   // 16x256 f32
#define OFF_CVO   52449280UL   // 256 f32
#define OFF_U     52453376UL   // 8x1024 f32
#define OFF_PART  52486144UL   // 256x1024 f32 = 1M
#define OFF_MSUM  53534720UL   // 256x2 f32

static __device__ __forceinline__ float bf2f(u16 u) {
    union { unsigned i; float f; } x; x.i = ((unsigned)u) << 16; return x.f;
}
static __device__ __forceinline__ u16 f2bf(float f) {
    union { float f; unsigned i; } x; x.f = f;
    unsigned r = x.i + 0x7FFFu + ((x.i >> 16) & 1u);
    return (u16)(r >> 16);
}
static __device__ __forceinline__ float2 bf2x2(int p) {
    union { unsigned i; float f; } a, b;
    a.i = ((unsigned)p) << 16;
    b.i = ((unsigned)p) & 0xFFFF0000u;
    float2 r; r.x = a.f; r.y = b.f; return r;
}

// Tiled-swizzled bf16 operand layout: element (rr in [0,128), cc in [0,64)) of tile
// (tr, ks) lives at u16 index (tr*KT + ks)*8192 + rr*64 + (((cc>>3) ^ (rr&7))<<3) + (cc&7).

// conv 128x64 f32 segment (row-major, leading dim lda) -> one swizzled bf16 tile
static __device__ __forceinline__ void conv_tile(const float* __restrict__ src, int lda,
                                                 u16* __restrict__ dst, int tid) {
#pragma unroll
    for (int i = 0; i < 4; ++i) {
        int it = i * 256 + tid;
        int rr = it >> 3, grp = it & 7;
        const float4* p = reinterpret_cast<const float4*>(&src[(size_t)rr * lda + grp * 8]);
        float4 v0 = p[0], v1 = p[1];
        int4 pk;
        pk.x = (int)f2bf(v0.x) | ((int)f2bf(v0.y) << 16);
        pk.y = (int)f2bf(v0.z) | ((int)f2bf(v0.w) << 16);
        pk.z = (int)f2bf(v1.x) | ((int)f2bf(v1.y) << 16);
        pk.w = (int)f2bf(v1.z) | ((int)f2bf(v1.w) << 16);
        *reinterpret_cast<int4*>(&dst[rr * 64 + ((grp ^ (rr & 7)) << 3)]) = pk;
    }
}

// ================= K1: operand prep =================
// blk 0..511    : xb  (mt = blk>>2, ks = blk&3)
// blk 512..575  : WiT transpose -> WiTb
// blk 576..639  : WoT transpose -> WoTb
// blk 640..1023 : Wq/Wk/Wv conv
// blk 1024..1087: cvec = Wk @ bq
// blk 1088..1103: cvop partials (bv @ Wo)
__global__ __launch_bounds__(256) void k1(const float* __restrict__ x,  u16* __restrict__ xb,
                                          const float* __restrict__ Wi, u16* __restrict__ WiTb,
                                          const float* __restrict__ Wo, u16* __restrict__ WoTb,
                                          const float* __restrict__ Wq, u16* __restrict__ Wqb,
                                          const float* __restrict__ Wk, u16* __restrict__ Wkb,
                                          const float* __restrict__ Wv, u16* __restrict__ Wvb,
                                          const float* __restrict__ bq, float* __restrict__ cvec,
                                          const float* __restrict__ bv, float* __restrict__ cvop) {
    __shared__ float t64[64][65];
    const int blk = blockIdx.x, tid = threadIdx.x;
    if (blk < 512) {
        const int mt = blk >> 2, ks = blk & 3;
        conv_tile(x + (size_t)mt * 128 * IN_ + ks * 64, IN_, xb + (size_t)(mt * 4 + ks) * 8192, tid);
    } else if (blk < 576) {
        // WiT[n][k] = Wi[k][n]; Wi is [256][1024].  KT=4.
        const int t = blk - 512;
        const int n0 = (t & 15) * 64, k0 = (t >> 4) * 64;
        const int cc = tid & 63, rr = tid >> 6;
#pragma unroll
        for (int p = 0; p < 16; ++p) { int r = p * 4 + rr; t64[r][cc] = Wi[(k0 + r) * 1024 + n0 + cc]; }
        __syncthreads();
        const int ks = k0 >> 6;
#pragma unroll
        for (int g = 0; g < 2; ++g) {
            int it = g * 256 + tid;
            int nn = it >> 3, grp = it & 7;
            int n = n0 + nn, tr = n >> 7, rrow = n & 127;
            int4 pk;
            pk.x = (int)f2bf(t64[grp * 8 + 0][nn]) | ((int)f2bf(t64[grp * 8 + 1][nn]) << 16);
            pk.y = (int)f2bf(t64[grp * 8 + 2][nn]) | ((int)f2bf(t64[grp * 8 + 3][nn]) << 16);
            pk.z = (int)f2bf(t64[grp * 8 + 4][nn]) | ((int)f2bf(t64[grp * 8 + 5][nn]) << 16);
            pk.w = (int)f2bf(t64[grp * 8 + 6][nn]) | ((int)f2bf(t64[grp * 8 + 7][nn]) << 16);
            *reinterpret_cast<int4*>(&WiTb[(size_t)(tr * 4 + ks) * 8192 + rrow * 64 + ((grp ^ (rrow & 7)) << 3)]) = pk;
        }
    } else if (blk < 640) {
        // WoT[o][e] = Wo[e][o]; Wo is [1024][256].  KT=16.
        const int t = blk - 576;
        const int o0 = (t & 3) * 64, e0 = (t >> 2) * 64;
        const int cc = tid & 63, rr = tid >> 6;
#pragma unroll
        for (int p = 0; p < 16; ++p) { int r = p * 4 + rr; t64[r][cc] = Wo[(e0 + r) * 256 + o0 + cc]; }
        __syncthreads();
        const int ks = e0 >> 6;
#pragma unroll
        for (int g = 0; g < 2; ++g) {
            int it = g * 256 + tid;
            int nn = it >> 3, grp = it & 7;
            int o = o0 + nn, tr = o >> 7, rrow = o & 127;
            int4 pk;
            pk.x = (int)f2bf(t64[grp * 8 + 0][nn]) | ((int)f2bf(t64[grp * 8 + 1][nn]) << 16);
            pk.y = (int)f2bf(t64[grp * 8 + 2][nn]) | ((int)f2bf(t64[grp * 8 + 3][nn]) << 16);
            pk.z = (int)f2bf(t64[grp * 8 + 4][nn]) | ((int)f2bf(t64[grp * 8 + 5][nn]) << 16);
            pk.w = (int)f2bf(t64[grp * 8 + 6][nn]) | ((int)f2bf(t64[grp * 8 + 7][nn]) << 16);
            *reinterpret_cast<int4*>(&WoTb[(size_t)(tr * 16 + ks) * 8192 + rrow * 64 + ((grp ^ (rrow & 7)) << 3)]) = pk;
        }
    } else if (blk < 1024) {
        const int seg = blk - 640;            // 0..383
        const int mat = seg >> 7;             // 0=Wq 1=Wk 2=Wv
        const int s2 = seg & 127;
        const int tr = s2 >> 4, ks = s2 & 15;
        const float* src = (mat == 0) ? Wq : (mat == 1) ? Wk : Wv;
        u16* dst = (mat == 0) ? Wqb : (mat == 1) ? Wkb : Wvb;
        conv_tile(src + (size_t)tr * 128 * D_ + ks * 64, D_, dst + (size_t)(tr * 16 + ks) * 8192, tid);
    } else if (blk < 1088) {
        // cvec[d] = sum_e Wk[d][e] * bq[e]
        const int b2 = blk - 1024;
        const int w = tid >> 6, l = tid & 63;
        const int dbase = b2 * 16 + w * 4;
        float4 qv[4];
#pragma unroll
        for (int p = 0; p < 4; ++p) qv[p] = *reinterpret_cast<const float4*>(&bq[p * 256 + l * 4]);
#pragma unroll
        for (int i = 0; i < 4; ++i) {
            const int d = dbase + i;
            const float* wr = &Wk[(size_t)d * 1024];
            float acc = 0.f;
#pragma unroll
            for (int p = 0; p < 4; ++p) {
                float4 wv = *reinterpret_cast<const float4*>(&wr[p * 256 + l * 4]);
                acc += wv.x * qv[p].x + wv.y * qv[p].y + wv.z * qv[p].z + wv.w * qv[p].w;
            }
#pragma unroll
            for (int s = 32; s > 0; s >>= 1) acc += __shfl_xor(acc, s);
            if (l == 0) cvec[d] = acc;
        }
    } else {
        // cvop[chunk][o] = sum_{e in chunk} bv[e]*Wo[e][o]
        const int b2 = blk - 1088;
        const int e0 = b2 * 64;
        float acc = 0.f;
        for (int e = 0; e < 64; ++e) acc += bv[e0 + e] * Wo[(size_t)(e0 + e) * 256 + tid];
        cvop[b2 * 256 + tid] = acc;
    }
}

// ---------------- staging: pre-swizzled bf16 tile (16 KB) -> LDS via DMA ----------------
static __device__ __forceinline__ void stage_bf(const u16* gtile, u16* lbuf, int w, int l) {
    const u16* g = gtile + w * 512 + l * 8;
    u16* lp = lbuf + w * 512;
#pragma unroll
    for (int i = 0; i < 4; ++i)
        __builtin_amdgcn_global_load_lds((const __attribute__((address_space(1))) void*)(g + i * 2048),
                                         (__attribute__((address_space(3))) void*)(lp + i * 2048), 16, 0, 0);
}

// ---------------- 128x128 MFMA tile, BK=64, single-buffer, both operands DMA ----------------
// OMODE: 0 = bf16 + bias, 1 = bf16 no bias, 2 = f32 no bias
template<int KT, int OMODE>
static __device__ __forceinline__ void mm128(
    const u16* __restrict__ Ab, const u16* __restrict__ Bb,
    u16* lA, u16* lB,
    const float* __restrict__ bias,
    u16* __restrict__ outb, float* __restrict__ outf, int ldo)
{
    const int tid = threadIdx.x, l = tid & 63, w = tid >> 6;
    const int wm = w >> 1, wn = w & 1;
    const int q = l >> 4, r = l & 15;
    f32x4 acc[4][4];
#pragma unroll
    for (int mt = 0; mt < 4; ++mt)
#pragma unroll
        for (int nt = 0; nt < 4; ++nt) acc[mt][nt] = (f32x4){0.f, 0.f, 0.f, 0.f};

    for (int ks = 0; ks < KT; ++ks) {
        if (ks) __syncthreads();
        stage_bf(Ab + (size_t)ks * 8192, lA, w, l);
        stage_bf(Bb + (size_t)ks * 8192, lB, w, l);
        __syncthreads();   // drains vmcnt (global_load_lds)
#pragma unroll
        for (int s = 0; s < 2; ++s) {
            bf16x8 af[4], bfr[4];
#pragma unroll
            for (int mt = 0; mt < 4; ++mt) {
                int row = wm * 64 + mt * 16 + r;
                af[mt] = *reinterpret_cast<const bf16x8*>(&lA[row * 64 + (((s * 4 + q) ^ (row & 7)) << 3)]);
            }
#pragma unroll
            for (int nt = 0; nt < 4; ++nt) {
                int row = wn * 64 + nt * 16 + r;
                bfr[nt] = *reinterpret_cast<const bf16x8*>(&lB[row * 64 + (((s * 4 + q) ^ (row & 7)) << 3)]);
            }
#pragma unroll
            for (int mt = 0; mt < 4; ++mt)
#pragma unroll
                for (int nt = 0; nt < 4; ++nt)
                    acc[mt][nt] = __builtin_amdgcn_mfma_f32_16x16x32_bf16(af[mt], bfr[nt], acc[mt][nt], 0, 0, 0);
        }
    }
    // epilogue.  C/D map: col=lane&15, row=(lane>>4)*4+j
#pragma unroll
    for (int nt = 0; nt < 4; ++nt) {
        int col = wn * 64 + nt * 16 + r;
        float bb = 0.f;
        if constexpr (OMODE == 0) bb = bias[col];
#pragma unroll
        for (int mt = 0; mt < 4; ++mt) {
#pragma unroll
            for (int j = 0; j < 4; ++j) {
                int row = wm * 64 + mt * 16 + q * 4 + j;
                float v = acc[mt][nt][j] + bb;
                if constexpr (OMODE == 2) outf[(size_t)row * ldo + col] = v;
                else                      outb[(size_t)row * ldo + col] = f2bf(v);
            }
        }
    }
}

// ================= K2: [Amat | Awo] first, then h-GEMM (XCD-swizzled) =================
__global__ __launch_bounds__(256) void k2(const u16* __restrict__ xb, const u16* __restrict__ WiTb,
                                          const float* __restrict__ bi, u16* __restrict__ h,
                                          const u16* __restrict__ Wqb, const u16* __restrict__ Wkb,
                                          u16* __restrict__ Amat,
                                          const u16* __restrict__ Wvb, const u16* __restrict__ WoTb,
                                          float* __restrict__ Awo) {
    __shared__ u16 lA[8192];
    __shared__ u16 lB[8192];
    const int blk = blockIdx.x;
    if (blk < 64) {
        // Amat = Wq @ Wk^T : long blocks first
        const int mt = blk >> 3, nt = blk & 7;
        mm128<16, 1>(Wqb + (size_t)mt * 16 * 8192, Wkb + (size_t)nt * 16 * 8192,
                     lA, lB, nullptr,
                     Amat + (size_t)mt * 128 * D_ + nt * 128, nullptr, D_);
    } else if (blk < 80) {
        const int t = blk - 64;
        const int mt = t >> 1, nt = t & 1;
        mm128<16, 2>(Wvb + (size_t)mt * 16 * 8192, WoTb + (size_t)nt * 16 * 8192,
                     lA, lB, nullptr,
                     nullptr, Awo + (size_t)mt * 128 * OUT_ + nt * 128, OUT_);
    } else {
        // h = x @ Wi + bi.  XCD-aware: xcd owns m-strip.
        const int j = blk - 80;
        const int xcd = j & 7, jj = j >> 3;
        const int mt = xcd * 16 + (jj >> 3), nt = jj & 7;
        mm128<4, 0>(xb + (size_t)mt * 4 * 8192, WiTb + (size_t)nt * 4 * 8192,
                    lA, lB, bi + nt * 128,
                    h + (size_t)mt * 128 * D_ + nt * 128, nullptr, D_);
    }
}

// ================= K3: u[b] = h_last[b] @ Amat + cvec ; cvo finish =================
__global__ __launch_bounds__(256) void k3(const u16* __restrict__ h, const u16* __restrict__ Amat,
                                          const float* __restrict__ cvec, float* __restrict__ u,
                                          const float* __restrict__ cvop, const float* __restrict__ bo,
                                          float* __restrict__ cvo) {
    const int blk = blockIdx.x, tid = threadIdx.x;
    if (blk < 128) {
        const int b = blk >> 4, dc = blk & 15;
        __shared__ float hl[1024];
        __shared__ float red[4][64];
        {
            const size_t hb = ((size_t)(b * S_ + S_ - 1)) * D_;
            int2 hv = *reinterpret_cast<const int2*>(&h[hb + tid * 4]);
            float2 p0 = bf2x2(hv.x), p1 = bf2x2(hv.y);
            hl[tid * 4 + 0] = p0.x; hl[tid * 4 + 1] = p0.y;
            hl[tid * 4 + 2] = p1.x; hl[tid * 4 + 3] = p1.y;
        }
        __syncthreads();
        const int dl = tid & 63, qd = tid >> 6;
        const int d = dc * 64 + dl;
        float ac[8] = {0.f, 0.f, 0.f, 0.f, 0.f, 0.f, 0.f, 0.f};
        for (int dp = qd * 256; dp < qd * 256 + 256; dp += 8) {
            float hh[8];
#pragma unroll
            for (int i = 0; i < 8; ++i) hh[i] = hl[dp + i];
#pragma unroll
            for (int i = 0; i < 8; ++i) ac[i] += hh[i] * bf2f(Amat[(size_t)(dp + i) * D_ + d]);
        }
        float acc = ((ac[0] + ac[1]) + (ac[2] + ac[3])) + ((ac[4] + ac[5]) + (ac[6] + ac[7]));
        red[qd][dl] = acc;
        __syncthreads();
        if (qd == 0) {
            float s = red[0][dl] + red[1][dl] + red[2][dl] + red[3][dl];
            u[b * D_ + d] = s + cvec[d];
        }
    } else {
        float s = bo[tid];
#pragma unroll
        for (int j = 0; j < 16; ++j) s += cvop[j * 256 + tid];
        cvo[tid] = s;
    }
}

// ================= K4: flash partial per (kc, b) over 64 rows =================
__global__ __launch_bounds__(256) void k4(const u16* __restrict__ h, const float* __restrict__ u,
                                          float* __restrict__ part, float* __restrict__ msum) {
    const int kc = blockIdx.x, b = blockIdx.y;
    const int tid = threadIdx.x, w = tid >> 6, l = tid & 63;
    __shared__ float sNp[RC_];
    float uv[16];
    {
        const float* ub = &u[b * D_ + l * 16];
#pragma unroll
        for (int p = 0; p < 4; ++p) {
            float4 v = *reinterpret_cast<const float4*>(&ub[p * 4]);
            uv[p * 4 + 0] = v.x; uv[p * 4 + 1] = v.y; uv[p * 4 + 2] = v.z; uv[p * 4 + 3] = v.w;
        }
    }
    const size_t base = ((size_t)(b * S_) + kc * RC_) * D_;
    for (int rr = 0; rr < 16; ++rr) {
        const int row = w * 16 + rr;
        const u16* hr = &h[base + (size_t)row * D_ + l * 16];
        int4 q0 = *reinterpret_cast<const int4*>(&hr[0]);
        int4 q1 = *reinterpret_cast<const int4*>(&hr[8]);
        float2 a0 = bf2x2(q0.x), a1 = bf2x2(q0.y), a2 = bf2x2(q0.z), a3 = bf2x2(q0.w);
        float2 c0 = bf2x2(q1.x), c1 = bf2x2(q1.y), c2 = bf2x2(q1.z), c3 = bf2x2(q1.w);
        float acc = a0.x * uv[0] + a0.y * uv[1] + a1.x * uv[2] + a1.y * uv[3]
                  + a2.x * uv[4] + a2.y * uv[5] + a3.x * uv[6] + a3.y * uv[7]
                  + c0.x * uv[8] + c0.y * uv[9] + c1.x * uv[10] + c1.y * uv[11]
                  + c2.x * uv[12] + c2.y * uv[13] + c3.x * uv[14] + c3.y * uv[15];
#pragma unroll
        for (int s = 32; s > 0; s >>= 1) acc += __shfl_xor(acc, s);
        if (l == 0) sNp[row] = acc * 0.03125f;   // 1/sqrt(1024)
    }
    __syncthreads();
    float sv = sNp[l];
    float mx = sv;
#pragma unroll
    for (int s = 32; s > 0; s >>= 1) mx = fmaxf(mx, __shfl_xor(mx, s));
    float p = __expf(sv - mx);
    float sum = p;
#pragma unroll
    for (int s = 32; s > 0; s >>= 1) sum += __shfl_xor(sum, s);
    __syncthreads();
    if (w == 0) sNp[l] = p;
    if (tid == 0) { msum[(kc * 8 + b) * 2] = mx; msum[(kc * 8 + b) * 2 + 1] = sum; }
    __syncthreads();
    const int d0 = tid * 4;
    float a0 = 0.f, a1 = 0.f, a2 = 0.f, a3 = 0.f;
    for (int k = 0; k < RC_; ++k) {
        float pk = sNp[k];
        int2 hv = *reinterpret_cast<const int2*>(&h[base + (size_t)k * D_ + d0]);
        float2 x0 = bf2x2(hv.x), x1 = bf2x2(hv.y);
        a0 += pk * x0.x; a1 += pk * x0.y; a2 += pk * x1.x; a3 += pk * x1.y;
    }
    float4 st = {a0, a1, a2, a3};
    *reinterpret_cast<float4*>(&part[((size_t)(kc * 8 + b)) * D_ + d0]) = st;
}

// ================= K5: combine partials -> hbar -> out = hbar@Awo + cvo =================
__global__ __launch_bounds__(256) void k5(const float* __restrict__ part, const float* __restrict__ msum,
                                          const float* __restrict__ Awo, const float* __restrict__ cvo,
                                          float* __restrict__ out) {
    const int b = blockIdx.x, tid = threadIdx.x, w = tid >> 6, l = tid & 63;
    __shared__ float hbar[1024];
    __shared__ float red[4][256];
    float m[KC_], sm[KC_];
    float M = -1e30f;
#pragma unroll
    for (int c = 0; c < KC_; ++c) {
        m[c] = msum[(c * 8 + b) * 2];
        sm[c] = msum[(c * 8 + b) * 2 + 1];
        M = fmaxf(M, m[c]);
    }
    float denom = 0.f;
    float wgt[KC_];
#pragma unroll
    for (int c = 0; c < KC_; ++c) { wgt[c] = __expf(m[c] - M); denom += wgt[c] * sm[c]; }
    const float inv = 1.f / denom;
    float h0 = 0.f, h1 = 0.f, h2 = 0.f, h3 = 0.f;
#pragma unroll
    for (int c = 0; c < KC_; ++c) {
        float4 pv = *reinterpret_cast<const float4*>(&part[((size_t)(c * 8 + b)) * D_ + tid * 4]);
        h0 += wgt[c] * pv.x; h1 += wgt[c] * pv.y; h2 += wgt[c] * pv.z; h3 += wgt[c] * pv.w;
    }
    hbar[tid * 4 + 0] = h0 * inv; hbar[tid * 4 + 1] = h1 * inv;
    hbar[tid * 4 + 2] = h2 * inv; hbar[tid * 4 + 3] = h3 * inv;
    __syncthreads();
    float o0 = 0.f, o1 = 0.f, o2 = 0.f, o3 = 0.f;
    for (int d = w * 256; d < w * 256 + 256; d += 4) {
        float4 hv = *reinterpret_cast<const float4*>(&hbar[d]);
#pragma unroll
        for (int j = 0; j < 4; ++j) {
            float hj = (j == 0) ? hv.x : (j == 1) ? hv.y : (j == 2) ? hv.z : hv.w;
            float4 av = *reinterpret_cast<const float4*>(&Awo[(size_t)(d + j) * OUT_ + l * 4]);
            o0 += hj * av.x; o1 += hj * av.y; o2 += hj * av.z; o3 += hj * av.w;
        }
    }
    red[w][l * 4 + 0] = o0; red[w][l * 4 + 1] = o1;
    red[w][l * 4 + 2] = o2; red[w][l * 4 + 3] = o3;
    __syncthreads();
    float r = red[0][tid] + red[1][tid] + red[2][tid] + red[3][tid] + cvo[tid];
    out[b * OUT_ + tid] = r;
}

extern "C" void kernel_launch(void* const* d_in, const int* in_sizes, int n_in,
                              void* d_out, int out_size, void* d_ws, size_t ws_size,
                              hipStream_t stream) {
    const float* x  = (const float*)d_in[0];
    const float* Wi = (const float*)d_in[1];
    const float* bi = (const float*)d_in[2];
    const float* Wq = (const float*)d_in[3];
    const float* bq = (const float*)d_in[4];
    const float* Wk = (const float*)d_in[5];
    // d_in[6] = bk : unused (softmax shift invariance)
    const float* Wv = (const float*)d_in[7];
    const float* bv = (const float*)d_in[8];
    const float* Wo = (const float*)d_in[9];
    const float* bo = (const float*)d_in[10];
    float* out = (float*)d_out;

    char* ws = (char*)d_ws;
    u16*   WiTb = (u16*)  (ws + OFF_WITB);
    u16*   WoTb = (u16*)  (ws + OFF_WOTB);
    u16*   xb   = (u16*)  (ws + OFF_XB);
    u16*   Wqb  = (u16*)  (ws + OFF_WQB);
    u16*   Wkb  = (u16*)  (ws + OFF_WKB);
    u16*   Wvb  = (u16*)  (ws + OFF_WVB);
    u16*   h    = (u16*)  (ws + OFF_H);
    u16*   Amat = (u16*)  (ws + OFF_AMAT);
    float* Awo  = (float*)(ws + OFF_AWO);
    float* cvec = (float*)(ws + OFF_C);
    float* cvop = (float*)(ws + OFF_CVOP);
    float* cvo  = (float*)(ws + OFF_CVO);
    float* uvec = (float*)(ws + OFF_U);
    float* part = (float*)(ws + OFF_PART);
    float* msum = (float*)(ws + OFF_MSUM);

    k1<<<1104,       256, 0, stream>>>(x, xb, Wi, WiTb, Wo, WoTb, Wq, Wqb, Wk, Wkb, Wv, Wvb,
                                       bq, cvec, bv, cvop);
    k2<<<1104,       256, 0, stream>>>(xb, WiTb, bi, h, Wqb, Wkb, Amat, Wvb, WoTb, Awo);
    k3<<<129,        256, 0, stream>>>(h, Amat, cvec, uvec, cvop, bo, cvo);
    k4<<<dim3(32,8), 256, 0, stream>>>(h, uvec, part, msum);
    k5<<<8,          256, 0, stream>>>(part, msum, Awo, cvo, out);
}